// Round 3
// baseline (934.690 us; speedup 1.0000x reference)
//
#include <hip/hip_runtime.h>
#include <math.h>

#define T_TOK 16384
#define DIM   2048
#define NE    64
#define NACT  8
#define ALPHA 1e-4f
#define EPSV  1e-9f
#define TAU   2e-4f

#define BT    32          // tokens per block
#define SLAB  128         // k per staged slab
#define PITCH 132         // x slab pitch (floats): (132*t+k)%32 = (4t+k)%32 -> conflict-free
#define CPIT  68          // combine-region pitch
#define APIT  65          // aff pitch: (65t+e)%32=(t+e)%32 -> 2-way max (free)

// ---------------------------------------------------------------------------
// Pass A: fp32 GEMM (x via LDS, W via global b128 gathers) + sigmoid + top-9
// near-tie marking + gates/idx/counts/P partials.
// Grid 512 x 256. Tile 32tok x 64exp, in-block split-K x4 (wave w owns the
// kk in [w*32,(w+1)*32) of each 128-k slab), lane grid 8tok x 8exp,
// per-thread 4tok x 8exp fp32 acc. Double-buffered x slabs.
// ---------------------------------------------------------------------------
__global__ __launch_bounds__(256, 2) void router_a(
        const float* __restrict__ x,
        const float* __restrict__ Wg,
        const float* __restrict__ bias,
        float* __restrict__ gates,
        float* __restrict__ idxf,
        float* __restrict__ Aout,
        float* __restrict__ gP,
        float* __restrict__ gC,
        int*   __restrict__ cntp,
        int*   __restrict__ list) {
    __shared__ __align__(16) float sX[2][BT * PITCH];   // 33.8 KB
    __shared__ __align__(16) float comb[4][BT * CPIT];  // 34.8 KB
    __shared__ float Pl[NE];
    __shared__ float Cl[NE];

    const int tid = threadIdx.x;
    const int tokBase = blockIdx.x * BT;
    const int wv   = tid >> 6;        // 0..3 : k sub-window
    const int lane = tid & 63;
    const int tg   = lane & 7;        // token group
    const int eg   = lane >> 3;       // expert group

    if (tid < NE) { Pl[tid] = 0.0f; Cl[tid] = 0.0f; }

    float acc[4][8];
#pragma unroll
    for (int i = 0; i < 4; ++i)
#pragma unroll
        for (int j = 0; j < 8; ++j) acc[i][j] = 0.0f;

    const float* wb[8];
#pragma unroll
    for (int j = 0; j < 8; ++j) wb[j] = Wg + (size_t)(eg + 8 * j) * DIM;

    // ---- prologue: stage slab 0 ----
    {
        float4 st[4];
#pragma unroll
        for (int q = 0; q < 4; ++q) {
            const int flat = (tid + q * 256) * 4;
            const int tok = flat >> 7, kk = flat & 127;
            st[q] = *(const float4*)(x + (size_t)(tokBase + tok) * DIM + kk);
        }
#pragma unroll
        for (int q = 0; q < 4; ++q) {
            const int flat = (tid + q * 256) * 4;
            const int tok = flat >> 7, kk = flat & 127;
            *(float4*)&sX[0][tok * PITCH + kk] = st[q];
        }
    }
    __syncthreads();

    const int NSLAB = DIM / SLAB;   // 16
    for (int c = 0; c < NSLAB; ++c) {
        const int buf = c & 1;
        float4 st[4];
        if (c + 1 < NSLAB) {
#pragma unroll
            for (int q = 0; q < 4; ++q) {
                const int flat = (tid + q * 256) * 4;
                const int tok = flat >> 7, kk = flat & 127;
                st[q] = *(const float4*)(x + (size_t)(tokBase + tok) * DIM
                                           + (c + 1) * SLAB + kk);
            }
        }

        const int kbase = c * SLAB + wv * 32;
#pragma unroll
        for (int step = 0; step < 8; ++step) {
            const int k4 = wv * 32 + step * 4;
            float4 xa[4];
#pragma unroll
            for (int i = 0; i < 4; ++i)
                xa[i] = *(const float4*)&sX[buf][(tg + 8 * i) * PITCH + k4];
            float4 wf[8];
#pragma unroll
            for (int j = 0; j < 8; ++j)
                wf[j] = *(const float4*)(wb[j] + kbase + step * 4);
#pragma unroll
            for (int i = 0; i < 4; ++i)
#pragma unroll
                for (int j = 0; j < 8; ++j) {
                    acc[i][j] = fmaf(xa[i].x, wf[j].x, acc[i][j]);
                    acc[i][j] = fmaf(xa[i].y, wf[j].y, acc[i][j]);
                    acc[i][j] = fmaf(xa[i].z, wf[j].z, acc[i][j]);
                    acc[i][j] = fmaf(xa[i].w, wf[j].w, acc[i][j]);
                }
        }

        if (c + 1 < NSLAB) {
#pragma unroll
            for (int q = 0; q < 4; ++q) {
                const int flat = (tid + q * 256) * 4;
                const int tok = flat >> 7, kk = flat & 127;
                *(float4*)&sX[buf ^ 1][tok * PITCH + kk] = st[q];
            }
        }
        __syncthreads();
    }

    // ---- cross-wave combine ----
#pragma unroll
    for (int i = 0; i < 4; ++i)
#pragma unroll
        for (int j = 0; j < 8; ++j)
            comb[wv][(tg + 8 * i) * CPIT + eg + 8 * j] = acc[i][j];
    __syncthreads();

    // thread -> (t, e0): final sum of 4 partials, sigmoid, dump
    float* aff = &comb[0][0];   // alias region 0 (safe: reads done before writes)
    {
        const int t = tid >> 3;
        const int e0 = (tid & 7) * 8;
        float v[8];
#pragma unroll
        for (int e = 0; e < 8; ++e) {
            float s = 0.0f;
#pragma unroll
            for (int w = 0; w < 4; ++w) s += comb[w][t * CPIT + e0 + e];
            v[e] = 1.0f / (1.0f + expf(-s));
        }
        __syncthreads();   // all comb reads done before aff overwrite
#pragma unroll
        for (int e = 0; e < 8; ++e) aff[t * APIT + e0 + e] = v[e];
        // dump fp32 affinity for the fixup pass
        *(float4*)(Aout + (size_t)(tokBase + t) * NE + e0)     = *(float4*)&v[0];
        *(float4*)(Aout + (size_t)(tokBase + t) * NE + e0 + 4) = *(float4*)&v[4];
    }
    __syncthreads();

    // ---- top-k + marking: wave wv owns tokens wv*8 .. wv*8+7 ----
    const float b = bias[lane];
    float pacc = 0.0f;
    float cacc = 0.0f;

    for (int it = 0; it < 8; ++it) {
        const int t = wv * 8 + it;
        const float a = aff[t * APIT + lane];

        float rs = a;
#pragma unroll
        for (int off = 32; off; off >>= 1) rs += __shfl_xor(rs, off, 64);
        pacc += a / (rs + EPSV);

        float s = a + b;
        float gk[NACT];
        int   ik[NACT];
        float gsum = 0.0f;
        float prevv = 0.0f, gmin = 1e30f;
        int   selcnt = 0;

#pragma unroll
        for (int k = 0; k < 9; ++k) {
            float v = s;
            int  vi = lane;
#pragma unroll
            for (int off = 32; off; off >>= 1) {
                const float ov = __shfl_xor(v, off, 64);
                const int   oi = __shfl_xor(vi, off, 64);
                if (ov > v || (ov == v && oi < vi)) { v = ov; vi = oi; }
            }
            if (k > 0) gmin = fminf(gmin, prevv - v);
            prevv = v;
            if (k < 8) {
                const float ga = __shfl(a, vi, 64);
                gk[k] = ga; ik[k] = vi; gsum += ga;
                if (lane == vi) { s = -INFINITY; selcnt++; }
            }
        }

        const bool marked = (gmin < TAU);
        if (!marked) cacc += (float)selcnt;

        if (lane == 0) {
            const int gt = tokBase + t;
            const float inv = 1.0f / (gsum + EPSV);
#pragma unroll
            for (int k = 0; k < NACT; ++k) {
                gates[(size_t)gt * NACT + k] = gk[k] * inv;
                idxf [(size_t)gt * NACT + k] = (float)ik[k];
            }
            if (marked) {
                const int slot = atomicAdd(cntp, 1);
                list[slot] = gt;
            }
        }
    }

    atomicAdd(&Pl[lane], pacc);
    atomicAdd(&Cl[lane], cacc);
    __syncthreads();
    if (tid < NE) {
        atomicAdd(&gP[tid], Pl[tid]);
        atomicAdd(&gC[tid], Cl[tid]);
    }
}

// ---------------------------------------------------------------------------
// Pass B: fp64 fixup of marked tokens. One wave per token (grid-strided).
// Recompute experts with fp32 score >= v8 - TAU exactly in fp64, redo top-8.
// ---------------------------------------------------------------------------
__global__ __launch_bounds__(64) void fixup_k(
        const float* __restrict__ x,
        const float* __restrict__ Wg,
        const float* __restrict__ bias,
        const float* __restrict__ Aout,
        float* __restrict__ gates,
        float* __restrict__ idxf,
        float* __restrict__ gC,
        const int* __restrict__ cntp,
        const int* __restrict__ list) {
    const int lane = threadIdx.x;
    const int cnt = *cntp;

    for (int idx = blockIdx.x; idx < cnt; idx += gridDim.x) {
        const int t = list[idx];
        const float a32 = Aout[(size_t)t * NE + lane];
        const float bl  = bias[lane];
        const float s32 = a32 + bl;

        // fp32 v8 (same argmax as pass A -> deterministic identical values)
        float ss = s32;
        float v8 = 0.0f;
#pragma unroll
        for (int k = 0; k < 8; ++k) {
            float v = ss;
            int  vi = lane;
#pragma unroll
            for (int off = 32; off; off >>= 1) {
                const float ov = __shfl_xor(v, off, 64);
                const int   oi = __shfl_xor(vi, off, 64);
                if (ov > v || (ov == v && oi < vi)) { v = ov; vi = oi; }
            }
            v8 = v;
            if (lane == vi) ss = -INFINITY;
        }
        const float thr = v8 - TAU;

        unsigned long long mb = __ballot(s32 >= thr);

        double ad = (double)a32;
        double sd = (double)s32;
        const float* xr = x + (size_t)t * DIM;

        while (mb) {
            const int e = __ffsll(mb) - 1;
            mb &= mb - 1;
            const float* wr = Wg + (size_t)e * DIM;
            double z = 0.0;
#pragma unroll
            for (int m = 0; m < 8; ++m) {
                const int k = 4 * lane + 256 * m;
                const float4 xv = *(const float4*)(xr + k);
                const float4 wv = *(const float4*)(wr + k);
                z = fma((double)xv.x, (double)wv.x, z);
                z = fma((double)xv.y, (double)wv.y, z);
                z = fma((double)xv.z, (double)wv.z, z);
                z = fma((double)xv.w, (double)wv.w, z);
            }
#pragma unroll
            for (int off = 32; off; off >>= 1) z += __shfl_xor(z, off, 64);
            const double af = 1.0 / (1.0 + exp(-z));
            if (lane == e) { ad = af; sd = af + (double)bl; }
        }

        // final fp64 top-8
        double ss2 = sd;
        double gk[NACT];
        int    ik[NACT];
        double gsum = 0.0;
#pragma unroll
        for (int k = 0; k < NACT; ++k) {
            double v = ss2;
            int   vi = lane;
#pragma unroll
            for (int off = 32; off; off >>= 1) {
                const double ov = __shfl_xor(v, off, 64);
                const int    oi = __shfl_xor(vi, off, 64);
                if (ov > v || (ov == v && oi < vi)) { v = ov; vi = oi; }
            }
            const double ga = __shfl(ad, vi, 64);
            gk[k] = ga; ik[k] = vi; gsum += ga;
            if (lane == vi) {
                ss2 = -INFINITY;
                atomicAdd(&gC[lane], 1.0f);
            }
        }

        if (lane == 0) {
            const double inv = 1.0 / (gsum + (double)EPSV);
#pragma unroll
            for (int k = 0; k < NACT; ++k) {
                gates[(size_t)t * NACT + k] = (float)(gk[k] * inv);
                idxf [(size_t)t * NACT + k] = (float)ik[k];
            }
        }
    }
}

// ---------------------------------------------------------------------------
__global__ void loss_k(const float* __restrict__ gP,
                       const float* __restrict__ gC,
                       float* __restrict__ out) {
    const int e = threadIdx.x;   // 64 threads
    const float f = gC[e] * ((float)NE / (float)(NACT * T_TOK));
    const float P = gP[e] / (float)T_TOK;
    float v = f * P;
#pragma unroll
    for (int off = 32; off; off >>= 1) v += __shfl_xor(v, off, 64);
    if (e == 0) out[0] = ALPHA * v;
}

__global__ void zero_k(float* __restrict__ p, int n) {
    const int i = blockIdx.x * blockDim.x + threadIdx.x;
    if (i < n) p[i] = 0.0f;
}

extern "C" void kernel_launch(void* const* d_in, const int* in_sizes, int n_in,
                              void* d_out, int out_size, void* d_ws, size_t ws_size,
                              hipStream_t stream) {
    const float* x    = (const float*)d_in[0];
    const float* Wg   = (const float*)d_in[1];
    const float* bias = (const float*)d_in[2];
    float* out = (float*)d_out;
    float* gates = out;
    float* idxf  = out + (size_t)T_TOK * NACT;
    float* loss  = out + 2 * (size_t)T_TOK * NACT;

    float* Aout = (float*)d_ws;                                   // 4 MB
    float* gP   = (float*)((char*)d_ws + (size_t)T_TOK * NE * 4); // 64
    float* gC   = gP + NE;                                        // 64
    int*   cntp = (int*)(gC + NE);                                // 1
    int*   list = cntp + 1;                                       // 16384

    zero_k<<<1, 192, 0, stream>>>(gP, 2 * NE + 1);
    router_a<<<T_TOK / BT, 256, 0, stream>>>(x, Wg, bias, gates, idxf,
                                             Aout, gP, gC, cntp, list);
    fixup_k<<<512, 64, 0, stream>>>(x, Wg, bias, Aout, gates, idxf,
                                    gC, cntp, list);
    loss_k<<<1, 64, 0, stream>>>(gP, gC, loss);
}

// Round 4
// 434.767 us; speedup vs baseline: 2.1499x; 2.1499x over previous
//
#include <hip/hip_runtime.h>
#include <math.h>

#define T_TOK 16384
#define DIM   2048
#define NE    64
#define NACT  8
#define ALPHA 1e-4f
#define EPSV  1e-9f
#define TAU   2.5e-4f

typedef __attribute__((ext_vector_type(8))) short bf16x8;
typedef __attribute__((ext_vector_type(4))) float f32x4;

// RNE float->bf16 (values are finite/small; no nan handling needed)
__device__ inline unsigned short bf16_rne(float f) {
    unsigned b = __float_as_uint(f);
    unsigned r = b + 0x7FFFu + ((b >> 16) & 1u);
    return (unsigned short)(r >> 16);
}

// Split 8 floats into hi (bf16 truncation) + lo (bf16 RNE of exact residual).
// xh+xl represents x to ~2^-17 relative: 3-term MFMA error sigma ~2e-5 << TAU.
__device__ inline void split8(const float4 a0, const float4 a1,
                              bf16x8& h, bf16x8& l) {
    float f[8] = {a0.x, a0.y, a0.z, a0.w, a1.x, a1.y, a1.z, a1.w};
#pragma unroll
    for (int i = 0; i < 8; ++i) {
        unsigned b  = __float_as_uint(f[i]);
        unsigned hb = b & 0xFFFF0000u;
        h[i] = (short)(hb >> 16);
        l[i] = (short)bf16_rne(f[i] - __uint_as_float(hb));
    }
}

// ---------------------------------------------------------------------------
// Pre-pass: split W (64x2048 fp32) into bf16 hi/lo arrays (done every launch).
// ---------------------------------------------------------------------------
__global__ __launch_bounds__(256) void wsplit(const float* __restrict__ W,
                                              unsigned short* __restrict__ Wh,
                                              unsigned short* __restrict__ Wl) {
    const int i = blockIdx.x * 256 + threadIdx.x;   // 131072 elements
    const float f = W[i];
    const unsigned b  = __float_as_uint(f);
    const unsigned hb = b & 0xFFFF0000u;
    Wh[i] = (unsigned short)(hb >> 16);
    Wl[i] = bf16_rne(f - __uint_as_float(hb));
}

// ---------------------------------------------------------------------------
// Pass A: affinity = sigmoid(x @ W^T) via bf16x3 MFMA, fragments direct from
// global (x converted in-register, W pre-split). Then per-wave top-8 + gate
// normalization + near-tie marking + balance-loss partials.
// Grid 256 x 256 (1 block/CU). Wave = 16 tok x 64 exp = 4 C-tiles of
// 16x16x32; K-loop 64 steps, 2-slot register pipeline.
// MFMA 16x16x32 bf16 layouts (m89/m120-verified):
//   A[m=lane&15][k=(lane>>4)*8+j], B[n=lane&15][k=(lane>>4)*8+j],
//   C: col(n)=lane&15, row(m)=(lane>>4)*4+reg.
// ---------------------------------------------------------------------------
__global__ __launch_bounds__(256) void router_a(
        const float* __restrict__ x,
        const unsigned short* __restrict__ Wh,
        const unsigned short* __restrict__ Wl,
        const float* __restrict__ bias,
        float* __restrict__ gates,
        float* __restrict__ idxf,
        float* __restrict__ Aout,
        float* __restrict__ gP,
        float* __restrict__ gC,
        int*   __restrict__ cntp,
        int*   __restrict__ list) {
    __shared__ float aff[64 * 65];   // block: 64 tokens x 64 experts, pitch 65
    __shared__ float Pl[NE];
    __shared__ float Cl[NE];

    const int tid  = threadIdx.x;
    const int wv   = tid >> 6;
    const int lane = tid & 63;
    const int c15  = lane & 15;
    const int q    = lane >> 4;
    const int tok0 = blockIdx.x * 64 + wv * 16;

    if (tid < NE) { Pl[tid] = 0.0f; Cl[tid] = 0.0f; }

    // fragment source pointers
    const float* xp = x + (size_t)(tok0 + c15) * DIM + q * 8;
    const unsigned short* whp[4];
    const unsigned short* wlp[4];
#pragma unroll
    for (int j = 0; j < 4; ++j) {
        whp[j] = Wh + (size_t)(16 * j + c15) * DIM + q * 8;
        wlp[j] = Wl + (size_t)(16 * j + c15) * DIM + q * 8;
    }

    f32x4 acc[4];
#pragma unroll
    for (int j = 0; j < 4; ++j) acc[j] = (f32x4){0.f, 0.f, 0.f, 0.f};

    float4 ra[2][2];
    bf16x8 rh[2][4], rl[2][4];

#define LOADSTEP(s, c) {                                                  \
        const float* xpc = xp + 32 * (c);                                 \
        ra[s][0] = *(const float4*)xpc;                                   \
        ra[s][1] = *(const float4*)(xpc + 4);                             \
        _Pragma("unroll")                                                 \
        for (int j = 0; j < 4; ++j) {                                     \
            rh[s][j] = *(const bf16x8*)(whp[j] + 32 * (c));               \
            rl[s][j] = *(const bf16x8*)(wlp[j] + 32 * (c));               \
        }                                                                 \
    }

#define COMPSTEP(s) {                                                     \
        bf16x8 ah, al;                                                    \
        split8(ra[s][0], ra[s][1], ah, al);                               \
        _Pragma("unroll")                                                 \
        for (int j = 0; j < 4; ++j) {                                     \
            acc[j] = __builtin_amdgcn_mfma_f32_16x16x32_bf16(ah, rh[s][j], acc[j], 0, 0, 0); \
            acc[j] = __builtin_amdgcn_mfma_f32_16x16x32_bf16(ah, rl[s][j], acc[j], 0, 0, 0); \
            acc[j] = __builtin_amdgcn_mfma_f32_16x16x32_bf16(al, rh[s][j], acc[j], 0, 0, 0); \
        }                                                                 \
    }

    LOADSTEP(0, 0);
    LOADSTEP(1, 1);
#pragma unroll 4
    for (int c = 0; c < 64; c += 2) {
        COMPSTEP(0);
        if (c + 2 < 64) LOADSTEP(0, c + 2);
        COMPSTEP(1);
        if (c + 3 < 64) LOADSTEP(1, c + 3);
    }
#undef LOADSTEP
#undef COMPSTEP

    // ---- sigmoid + C-layout scatter to LDS (wave-private rows) ----
#pragma unroll
    for (int j = 0; j < 4; ++j)
#pragma unroll
        for (int r = 0; r < 4; ++r) {
            const float v = 1.0f / (1.0f + expf(-acc[j][r]));
            aff[(wv * 16 + q * 4 + r) * 65 + 16 * j + c15] = v;
        }
    __syncthreads();   // Pl/Cl init + aff visibility

    // ---- per-wave top-8 over its 16 tokens ----
    const float b = bias[lane];
    float pacc = 0.0f;
    float cacc = 0.0f;

    for (int it = 0; it < 16; ++it) {
        const int tl = wv * 16 + it;
        const int gt = blockIdx.x * 64 + tl;
        const float a = aff[tl * 65 + lane];

        Aout[(size_t)gt * NE + lane] = a;   // for fixup pass

        float rs = a;
#pragma unroll
        for (int off = 32; off; off >>= 1) rs += __shfl_xor(rs, off, 64);
        pacc += a / (rs + EPSV);

        float s = a + b;
        float gk[NACT];
        int   ik[NACT];
        float gsum = 0.0f;
        float prevv = 0.0f, gmin = 1e30f;
        int   selcnt = 0;

#pragma unroll
        for (int k = 0; k < 9; ++k) {
            float v = s;
            int  vi = lane;
#pragma unroll
            for (int off = 32; off; off >>= 1) {
                const float ov = __shfl_xor(v, off, 64);
                const int   oi = __shfl_xor(vi, off, 64);
                if (ov > v || (ov == v && oi < vi)) { v = ov; vi = oi; }
            }
            if (k > 0) gmin = fminf(gmin, prevv - v);
            prevv = v;
            if (k < 8) {
                const float ga = __shfl(a, vi, 64);
                gk[k] = ga; ik[k] = vi; gsum += ga;
                if (lane == vi) { s = -INFINITY; selcnt++; }
            }
        }

        const bool marked = (gmin < TAU);
        if (!marked) cacc += (float)selcnt;

        if (lane == 0) {
            const float inv = 1.0f / (gsum + EPSV);
#pragma unroll
            for (int k = 0; k < NACT; ++k) {
                gates[(size_t)gt * NACT + k] = gk[k] * inv;
                idxf [(size_t)gt * NACT + k] = (float)ik[k];
            }
            if (marked) {
                const int slot = atomicAdd(cntp, 1);
                list[slot] = gt;
            }
        }
    }

    atomicAdd(&Pl[lane], pacc);
    atomicAdd(&Cl[lane], cacc);
    __syncthreads();
    if (tid < NE) {
        atomicAdd(&gP[tid], Pl[tid]);
        atomicAdd(&gC[tid], Cl[tid]);
    }
}

// ---------------------------------------------------------------------------
// Pass B: fp64 fixup of marked tokens. One wave per token (grid-strided),
// x row hoisted into registers once per token.
// ---------------------------------------------------------------------------
__global__ __launch_bounds__(64) void fixup_k(
        const float* __restrict__ x,
        const float* __restrict__ Wg,
        const float* __restrict__ bias,
        const float* __restrict__ Aout,
        float* __restrict__ gates,
        float* __restrict__ idxf,
        float* __restrict__ gC,
        const int* __restrict__ cntp,
        const int* __restrict__ list) {
    const int lane = threadIdx.x;
    const int cnt = *cntp;

    for (int idx = blockIdx.x; idx < cnt; idx += gridDim.x) {
        const int t = list[idx];
        const float a32 = Aout[(size_t)t * NE + lane];
        const float bl  = bias[lane];
        const float s32 = a32 + bl;

        // hoist x row: 32 floats/lane, k = 4*lane + 256*m
        const float* xr = x + (size_t)t * DIM;
        float4 xv[8];
#pragma unroll
        for (int m = 0; m < 8; ++m) xv[m] = *(const float4*)(xr + 4 * lane + 256 * m);

        // fp32 v8 (same values as pass A -> identical ordering)
        float ss = s32;
        float v8 = 0.0f;
#pragma unroll
        for (int k = 0; k < 8; ++k) {
            float v = ss;
            int  vi = lane;
#pragma unroll
            for (int off = 32; off; off >>= 1) {
                const float ov = __shfl_xor(v, off, 64);
                const int   oi = __shfl_xor(vi, off, 64);
                if (ov > v || (ov == v && oi < vi)) { v = ov; vi = oi; }
            }
            v8 = v;
            if (lane == vi) ss = -INFINITY;
        }
        const float thr = v8 - TAU;

        unsigned long long mb = __ballot(s32 >= thr);

        double ad = (double)a32;
        double sd = (double)s32;

        while (mb) {
            const int e = __ffsll(mb) - 1;
            mb &= mb - 1;
            const float* wr = Wg + (size_t)e * DIM;
            double z = 0.0;
#pragma unroll
            for (int m = 0; m < 8; ++m) {
                const float4 wv = *(const float4*)(wr + 4 * lane + 256 * m);
                z = fma((double)xv[m].x, (double)wv.x, z);
                z = fma((double)xv[m].y, (double)wv.y, z);
                z = fma((double)xv[m].z, (double)wv.z, z);
                z = fma((double)xv[m].w, (double)wv.w, z);
            }
#pragma unroll
            for (int off = 32; off; off >>= 1) z += __shfl_xor(z, off, 64);
            const double af = 1.0 / (1.0 + exp(-z));
            if (lane == e) { ad = af; sd = af + (double)bl; }
        }

        // final fp64 top-8
        double ss2 = sd;
        double gk[NACT];
        int    ik[NACT];
        double gsum = 0.0;
#pragma unroll
        for (int k = 0; k < NACT; ++k) {
            double v = ss2;
            int   vi = lane;
#pragma unroll
            for (int off = 32; off; off >>= 1) {
                const double ov = __shfl_xor(v, off, 64);
                const int    oi = __shfl_xor(vi, off, 64);
                if (ov > v || (ov == v && oi < vi)) { v = ov; vi = oi; }
            }
            const double ga = __shfl(ad, vi, 64);
            gk[k] = ga; ik[k] = vi; gsum += ga;
            if (lane == vi) {
                ss2 = -INFINITY;
                atomicAdd(&gC[lane], 1.0f);
            }
        }

        if (lane == 0) {
            const double inv = 1.0 / (gsum + (double)EPSV);
#pragma unroll
            for (int k = 0; k < NACT; ++k) {
                gates[(size_t)t * NACT + k] = (float)(gk[k] * inv);
                idxf [(size_t)t * NACT + k] = (float)ik[k];
            }
        }
    }
}

// ---------------------------------------------------------------------------
__global__ void loss_k(const float* __restrict__ gP,
                       const float* __restrict__ gC,
                       float* __restrict__ out) {
    const int e = threadIdx.x;   // 64 threads
    const float f = gC[e] * ((float)NE / (float)(NACT * T_TOK));
    const float P = gP[e] / (float)T_TOK;
    float v = f * P;
#pragma unroll
    for (int off = 32; off; off >>= 1) v += __shfl_xor(v, off, 64);
    if (e == 0) out[0] = ALPHA * v;
}

__global__ void zero_k(float* __restrict__ p, int n) {
    const int i = blockIdx.x * blockDim.x + threadIdx.x;
    if (i < n) p[i] = 0.0f;
}

extern "C" void kernel_launch(void* const* d_in, const int* in_sizes, int n_in,
                              void* d_out, int out_size, void* d_ws, size_t ws_size,
                              hipStream_t stream) {
    const float* x    = (const float*)d_in[0];
    const float* Wg   = (const float*)d_in[1];
    const float* bias = (const float*)d_in[2];
    float* out = (float*)d_out;
    float* gates = out;
    float* idxf  = out + (size_t)T_TOK * NACT;
    float* loss  = out + 2 * (size_t)T_TOK * NACT;

    // ws layout (16B-aligned pieces first)
    unsigned short* Wh = (unsigned short*)d_ws;            // 256 KB
    unsigned short* Wl = Wh + (size_t)NE * DIM;            // 256 KB
    float* Aout = (float*)(Wl + (size_t)NE * DIM);         // 4 MB
    float* gP   = Aout + (size_t)T_TOK * NE;               // 64
    float* gC   = gP + NE;                                 // 64
    int*   cntp = (int*)(gC + NE);                         // 1
    int*   list = cntp + 1;                                // 16384

    zero_k<<<1, 192, 0, stream>>>(gP, 2 * NE + 1);
    wsplit<<<(NE * DIM) / 256, 256, 0, stream>>>(Wg, Wh, Wl);
    router_a<<<T_TOK / 64, 256, 0, stream>>>(x, Wh, Wl, bias, gates, idxf,
                                             Aout, gP, gC, cntp, list);
    fixup_k<<<2048, 64, 0, stream>>>(x, Wg, bias, Aout, gates, idxf,
                                     gC, cntp, list);
    loss_k<<<1, 64, 0, stream>>>(gP, gC, loss);
}

// Round 5
// 371.906 us; speedup vs baseline: 2.5132x; 1.1690x over previous
//
#include <hip/hip_runtime.h>
#include <math.h>

#define T_TOK 16384
#define DIM   2048
#define NE    64
#define NACT  8
#define ALPHA 1e-4f
#define EPSV  1e-9f
#define TAU   2.5e-4f

typedef __attribute__((ext_vector_type(8))) short bf16x8;
typedef __attribute__((ext_vector_type(4))) float f32x4;

// RNE float->bf16 (values finite/small; no nan handling needed)
__device__ inline unsigned short bf16_rne(float f) {
    unsigned b = __float_as_uint(f);
    unsigned r = b + 0x7FFFu + ((b >> 16) & 1u);
    return (unsigned short)(r >> 16);
}

// Split 8 floats into hi (bf16 truncation) + lo (bf16 RNE of residual).
// x ~= xh+xl to ~2^-17 relative: 3-term MFMA logit sigma ~1.5e-5 << TAU.
__device__ inline void split8(const float4 a0, const float4 a1,
                              bf16x8& h, bf16x8& l) {
    float f[8] = {a0.x, a0.y, a0.z, a0.w, a1.x, a1.y, a1.z, a1.w};
#pragma unroll
    for (int i = 0; i < 8; ++i) {
        unsigned b  = __float_as_uint(f[i]);
        unsigned hb = b & 0xFFFF0000u;
        h[i] = (short)(hb >> 16);
        l[i] = (short)bf16_rne(f[i] - __uint_as_float(hb));
    }
}

// ---------------------------------------------------------------------------
// Pre-pass: split W (64x2048 fp32) into bf16 hi/lo arrays.
// ---------------------------------------------------------------------------
__global__ __launch_bounds__(256) void wsplit(const float* __restrict__ W,
                                              unsigned short* __restrict__ Wh,
                                              unsigned short* __restrict__ Wl) {
    const int i = blockIdx.x * 256 + threadIdx.x;   // 131072 elements
    const float f = W[i];
    const unsigned b  = __float_as_uint(f);
    const unsigned hb = b & 0xFFFF0000u;
    Wh[i] = (unsigned short)(hb >> 16);
    Wl[i] = bf16_rne(f - __uint_as_float(hb));
}

// ---------------------------------------------------------------------------
// Pass A: affinity = sigmoid(x @ W^T) via bf16x3 MFMA, fragments direct from
// global. K-split x4 across the block's waves (wave w owns k in
// [512w,512w+512)), partials combined through LDS. Grid 1024 x 256 ->
// 4 blocks/CU, 16 waves/CU (the round-4 kernel had 1 wave/SIMD and died of
// latency). Then per-wave top-8 + near-tie marking + loss partials.
// MFMA 16x16x32 bf16 layouts (m89/m120-verified):
//   A[m=lane&15][k=(lane>>4)*8+j], B[n=lane&15][k=(lane>>4)*8+j],
//   C: col(n)=lane&15, row(m)=(lane>>4)*4+reg.
// ---------------------------------------------------------------------------
__global__ __launch_bounds__(256, 4) void router_a(
        const float* __restrict__ x,
        const unsigned short* __restrict__ Wh,
        const unsigned short* __restrict__ Wl,
        const float* __restrict__ bias,
        float* __restrict__ gates,
        float* __restrict__ idxf,
        float* __restrict__ Aout,
        float* __restrict__ gP,
        float* __restrict__ gC,
        int*   __restrict__ cntp,
        int*   __restrict__ list) {
    __shared__ __align__(16) float comb[4 * 16 * 68];   // 17408 B, pitch 68
    __shared__ __align__(16) float aff[16 * 68];        //  4352 B, pitch 68
    __shared__ float Pl[NE];
    __shared__ float Cl[NE];

    const int tid  = threadIdx.x;
    const int wv   = tid >> 6;       // K-slice owner
    const int lane = tid & 63;
    const int c15  = lane & 15;
    const int q    = lane >> 4;
    const int tokBase = blockIdx.x * 16;

    if (tid < NE) { Pl[tid] = 0.0f; Cl[tid] = 0.0f; }

    const int kb = wv * 512;
    const float* xp = x + (size_t)(tokBase + c15) * DIM + kb + q * 8;
    const unsigned short* whp[4];
    const unsigned short* wlp[4];
#pragma unroll
    for (int j = 0; j < 4; ++j) {
        whp[j] = Wh + (size_t)(16 * j + c15) * DIM + kb + q * 8;
        wlp[j] = Wl + (size_t)(16 * j + c15) * DIM + kb + q * 8;
    }

    f32x4 acc[4];
#pragma unroll
    for (int j = 0; j < 4; ++j) acc[j] = (f32x4){0.f, 0.f, 0.f, 0.f};

    float4 ra[2][2];
    bf16x8 rh[2][4], rl[2][4];

#define LOADSTEP(s, c) {                                                  \
        const float* xpc = xp + 32 * (c);                                 \
        ra[s][0] = *(const float4*)xpc;                                   \
        ra[s][1] = *(const float4*)(xpc + 4);                             \
        _Pragma("unroll")                                                 \
        for (int j = 0; j < 4; ++j) {                                     \
            rh[s][j] = *(const bf16x8*)(whp[j] + 32 * (c));               \
            rl[s][j] = *(const bf16x8*)(wlp[j] + 32 * (c));               \
        }                                                                 \
    }

#define COMPSTEP(s) {                                                     \
        bf16x8 ah, al;                                                    \
        split8(ra[s][0], ra[s][1], ah, al);                               \
        _Pragma("unroll")                                                 \
        for (int j = 0; j < 4; ++j) {                                     \
            acc[j] = __builtin_amdgcn_mfma_f32_16x16x32_bf16(ah, rh[s][j], acc[j], 0, 0, 0); \
            acc[j] = __builtin_amdgcn_mfma_f32_16x16x32_bf16(ah, rl[s][j], acc[j], 0, 0, 0); \
            acc[j] = __builtin_amdgcn_mfma_f32_16x16x32_bf16(al, rh[s][j], acc[j], 0, 0, 0); \
        }                                                                 \
    }

    LOADSTEP(0, 0);
    LOADSTEP(1, 1);
#pragma unroll 2
    for (int c = 0; c < 16; c += 2) {
        COMPSTEP(0);
        if (c + 2 < 16) LOADSTEP(0, c + 2);
        COMPSTEP(1);
        if (c + 3 < 16) LOADSTEP(1, c + 3);
    }
#undef LOADSTEP
#undef COMPSTEP

    // ---- write K-partials (C-layout) to LDS ----
#pragma unroll
    for (int j = 0; j < 4; ++j)
#pragma unroll
        for (int r = 0; r < 4; ++r)
            comb[wv * 1088 + (q * 4 + r) * 68 + 16 * j + c15] = acc[j][r];
    __syncthreads();

    // ---- combine 4 partials + sigmoid + dump ----
    {
        const int t  = tid >> 4;
        const int e0 = (tid & 15) * 4;
        const float4 s0 = *(const float4*)&comb[0 * 1088 + t * 68 + e0];
        const float4 s1 = *(const float4*)&comb[1 * 1088 + t * 68 + e0];
        const float4 s2 = *(const float4*)&comb[2 * 1088 + t * 68 + e0];
        const float4 s3 = *(const float4*)&comb[3 * 1088 + t * 68 + e0];
        float4 af;
        af.x = 1.0f / (1.0f + expf(-(s0.x + s1.x + s2.x + s3.x)));
        af.y = 1.0f / (1.0f + expf(-(s0.y + s1.y + s2.y + s3.y)));
        af.z = 1.0f / (1.0f + expf(-(s0.z + s1.z + s2.z + s3.z)));
        af.w = 1.0f / (1.0f + expf(-(s0.w + s1.w + s2.w + s3.w)));
        *(float4*)&aff[t * 68 + e0] = af;
        *(float4*)(Aout + (size_t)(tokBase + t) * NE + e0) = af;
    }
    __syncthreads();

    // ---- top-8 + marking: wave wv owns tokens 4wv..4wv+3 ----
    const float b = bias[lane];
    float pacc = 0.0f;
    float cacc = 0.0f;

    for (int it = 0; it < 4; ++it) {
        const int tl = wv * 4 + it;
        const int gt = tokBase + tl;
        const float a = aff[tl * 68 + lane];

        float rs = a;
#pragma unroll
        for (int off = 32; off; off >>= 1) rs += __shfl_xor(rs, off, 64);
        pacc += a / (rs + EPSV);

        float s = a + b;
        float gk[NACT];
        int   ik[NACT];
        float gsum = 0.0f;
        float prevv = 0.0f, gmin = 1e30f;
        int   selcnt = 0;

#pragma unroll
        for (int k = 0; k < 9; ++k) {
            float v = s;
            int  vi = lane;
#pragma unroll
            for (int off = 32; off; off >>= 1) {
                const float ov = __shfl_xor(v, off, 64);
                const int   oi = __shfl_xor(vi, off, 64);
                if (ov > v || (ov == v && oi < vi)) { v = ov; vi = oi; }
            }
            if (k > 0) gmin = fminf(gmin, prevv - v);
            prevv = v;
            if (k < 8) {
                const float ga = __shfl(a, vi, 64);
                gk[k] = ga; ik[k] = vi; gsum += ga;
                if (lane == vi) { s = -INFINITY; selcnt++; }
            }
        }

        const bool marked = (gmin < TAU);
        if (!marked) cacc += (float)selcnt;

        if (lane == 0) {
            const float inv = 1.0f / (gsum + EPSV);
#pragma unroll
            for (int k = 0; k < NACT; ++k) {
                gates[(size_t)gt * NACT + k] = gk[k] * inv;
                idxf [(size_t)gt * NACT + k] = (float)ik[k];
            }
            if (marked) {
                const int slot = atomicAdd(cntp, 1);
                list[slot] = gt;
            }
        }
    }

    atomicAdd(&Pl[lane], pacc);
    atomicAdd(&Cl[lane], cacc);
    __syncthreads();
    if (tid < NE) {
        atomicAdd(&gP[tid], Pl[tid]);
        atomicAdd(&gC[tid], Cl[tid]);
    }
}

// ---------------------------------------------------------------------------
// Pass B: fp64 fixup of marked tokens. One wave per token (grid-strided).
// Chain-closure candidate set: scan fp32 top-16, recompute in fp64 only the
// connected components (adjacent gap < TAU) touching ranks 0..8 — typically
// exactly 2 experts, processed two-at-a-time with interleaved loads.
// Non-recomputed values keep fp32 (their gaps are >= TAU >> fp64 shift).
// ---------------------------------------------------------------------------
__global__ __launch_bounds__(64) void fixup_k(
        const float* __restrict__ x,
        const float* __restrict__ Wg,
        const float* __restrict__ bias,
        const float* __restrict__ Aout,
        float* __restrict__ gates,
        float* __restrict__ idxf,
        float* __restrict__ gC,
        const int* __restrict__ cntp,
        const int* __restrict__ list) {
    const int lane = threadIdx.x;
    const int cnt = *cntp;
    float cacc = 0.0f;

    for (int idx = blockIdx.x; idx < cnt; idx += gridDim.x) {
        const int t = list[idx];
        const float a32 = Aout[(size_t)t * NE + lane];
        const float bl  = bias[lane];
        const float s32 = a32 + bl;

        // hoist x row: k = 4*lane + 256*m
        const float* xr = x + (size_t)t * DIM;
        float4 xv[8];
#pragma unroll
        for (int m = 0; m < 8; ++m) xv[m] = *(const float4*)(xr + 4 * lane + 256 * m);

        // fp32 scan of top-16 (butterfly argmax leaves max in all lanes)
        float vr[16];
        int   ir[16];
        float ss = s32;
#pragma unroll
        for (int k = 0; k < 16; ++k) {
            float v = ss;
            int  vi = lane;
#pragma unroll
            for (int off = 32; off; off >>= 1) {
                const float ov = __shfl_xor(v, off, 64);
                const int   oi = __shfl_xor(vi, off, 64);
                if (ov > v || (ov == v && oi < vi)) { v = ov; vi = oi; }
            }
            vr[k] = v; ir[k] = vi;
            if (lane == vi) ss = -INFINITY;
        }

        // chain closure: components of adjacent gap < TAU touching ranks 0..8
        bool needs[16];
#pragma unroll
        for (int k = 0; k < 16; ++k) needs[k] = false;
#pragma unroll
        for (int k = 1; k <= 8; ++k)
            if (vr[k - 1] - vr[k] < TAU) { needs[k - 1] = true; needs[k] = true; }
#pragma unroll
        for (int k = 9; k < 16; ++k)
            if (needs[k - 1] && (vr[k - 1] - vr[k] < TAU)) needs[k] = true;

        unsigned long long mb = 0ull;
#pragma unroll
        for (int k = 0; k < 16; ++k)
            if (needs[k]) mb |= (1ull << ir[k]);

        // fp64 recompute of candidates, two at a time
        double ad = (double)a32;
        while (mb) {
            const int e0 = __ffsll(mb) - 1;
            mb &= mb - 1;
            int e1 = -1;
            if (mb) { e1 = __ffsll(mb) - 1; mb &= mb - 1; }
            const float* wr0 = Wg + (size_t)e0 * DIM;
            const float* wr1 = Wg + (size_t)((e1 >= 0) ? e1 : e0) * DIM;
            float4 w0[8], w1[8];
#pragma unroll
            for (int m = 0; m < 8; ++m) {
                w0[m] = *(const float4*)(wr0 + 4 * lane + 256 * m);
                w1[m] = *(const float4*)(wr1 + 4 * lane + 256 * m);
            }
            double z0 = 0.0, z1 = 0.0;
#pragma unroll
            for (int m = 0; m < 8; ++m) {
                z0 = fma((double)xv[m].x, (double)w0[m].x, z0);
                z0 = fma((double)xv[m].y, (double)w0[m].y, z0);
                z0 = fma((double)xv[m].z, (double)w0[m].z, z0);
                z0 = fma((double)xv[m].w, (double)w0[m].w, z0);
                z1 = fma((double)xv[m].x, (double)w1[m].x, z1);
                z1 = fma((double)xv[m].y, (double)w1[m].y, z1);
                z1 = fma((double)xv[m].z, (double)w1[m].z, z1);
                z1 = fma((double)xv[m].w, (double)w1[m].w, z1);
            }
#pragma unroll
            for (int off = 32; off; off >>= 1) {
                z0 += __shfl_xor(z0, off, 64);
                z1 += __shfl_xor(z1, off, 64);
            }
            const double af0 = 1.0 / (1.0 + exp(-z0));
            if (lane == e0) ad = af0;
            if (e1 >= 0) {
                const double af1 = 1.0 / (1.0 + exp(-z1));
                if (lane == e1) ad = af1;
            }
        }

        // final fp64 top-8 over mixed (fp64 candidates, fp32 others)
        double sd = ad + (double)bl;
        double gk[NACT];
        int    ik[NACT];
        double gsum = 0.0;
#pragma unroll
        for (int k = 0; k < NACT; ++k) {
            double v = sd;
            int   vi = lane;
#pragma unroll
            for (int off = 32; off; off >>= 1) {
                const double ov = __shfl_xor(v, off, 64);
                const int    oi = __shfl_xor(vi, off, 64);
                if (ov > v || (ov == v && oi < vi)) { v = ov; vi = oi; }
            }
            const double ga = __shfl(ad, vi, 64);
            gk[k] = ga; ik[k] = vi; gsum += ga;
            if (lane == vi) { sd = -INFINITY; cacc += 1.0f; }
        }

        if (lane == 0) {
            const double inv = 1.0 / (gsum + (double)EPSV);
#pragma unroll
            for (int k = 0; k < NACT; ++k) {
                gates[(size_t)t * NACT + k] = (float)(gk[k] * inv);
                idxf [(size_t)t * NACT + k] = (float)ik[k];
            }
        }
    }

    atomicAdd(&gC[lane], cacc);
}

// ---------------------------------------------------------------------------
__global__ void loss_k(const float* __restrict__ gP,
                       const float* __restrict__ gC,
                       float* __restrict__ out) {
    const int e = threadIdx.x;   // 64 threads
    const float f = gC[e] * ((float)NE / (float)(NACT * T_TOK));
    const float P = gP[e] / (float)T_TOK;
    float v = f * P;
#pragma unroll
    for (int off = 32; off; off >>= 1) v += __shfl_xor(v, off, 64);
    if (e == 0) out[0] = ALPHA * v;
}

__global__ void zero_k(float* __restrict__ p, int n) {
    const int i = blockIdx.x * blockDim.x + threadIdx.x;
    if (i < n) p[i] = 0.0f;
}

extern "C" void kernel_launch(void* const* d_in, const int* in_sizes, int n_in,
                              void* d_out, int out_size, void* d_ws, size_t ws_size,
                              hipStream_t stream) {
    const float* x    = (const float*)d_in[0];
    const float* Wg   = (const float*)d_in[1];
    const float* bias = (const float*)d_in[2];
    float* out = (float*)d_out;
    float* gates = out;
    float* idxf  = out + (size_t)T_TOK * NACT;
    float* loss  = out + 2 * (size_t)T_TOK * NACT;

    unsigned short* Wh = (unsigned short*)d_ws;            // 256 KB
    unsigned short* Wl = Wh + (size_t)NE * DIM;            // 256 KB
    float* Aout = (float*)(Wl + (size_t)NE * DIM);         // 4 MB
    float* gP   = Aout + (size_t)T_TOK * NE;               // 64
    float* gC   = gP + NE;                                 // 64
    int*   cntp = (int*)(gC + NE);                         // 1
    int*   list = cntp + 1;                                // 16384

    zero_k<<<1, 192, 0, stream>>>(gP, 2 * NE + 1);
    wsplit<<<(NE * DIM) / 256, 256, 0, stream>>>(Wg, Wh, Wl);
    router_a<<<T_TOK / 16, 256, 0, stream>>>(x, Wh, Wl, bias, gates, idxf,
                                             Aout, gP, gC, cntp, list);
    fixup_k<<<4096, 64, 0, stream>>>(x, Wg, bias, Aout, gates, idxf,
                                     gC, cntp, list);
    loss_k<<<1, 64, 0, stream>>>(gP, gC, loss);
}